// Round 11
// baseline (135.148 us; speedup 1.0000x reference)
//
#include <hip/hip_runtime.h>

// Problem constants (from reference)
constexpr int F     = 20;        // fields
constexpr int A     = 4;         // len(ACTION)
constexpr int M     = 4;         // sub-codebooks
constexpr int D     = 64;        // EMBED_DIM (= M * 16)
constexpr int MAXK  = 512;
constexpr int FIELD = 50000;
constexpr int V     = FIELD * F; // 1,000,000
constexpr int B     = 8192;
constexpr int G     = 8;         // (b,f) pairs per thread
// grid = B*F/G * 16 / 256 = 1280 blocks = exactly 5 blocks/CU on 256 CUs
// -> single residency round (5*4=20 waves/CU), no tail quantization.

typedef int i32x4 __attribute__((ext_vector_type(4)));

// 16 threads per (b,f); thread t owns output float4 at column t*4
// (m = t>>2). All 32 scattered kv gathers issue before any dependent
// codebook load; per-g codebook/compute/store reuses one v-register set.
//
// NOTE on stores: output stores are PLAIN (coherent). Nontemporal stores
// raced with the harness's 0xAA re-poison fill (dirty lines in per-XCD L2
// evicted after our around-cache store -> poison won; post-timing absmax
// 9.75 in R9). nt LOADS of never-modified inputs are safe and kept.
__global__ __launch_bounds__(256)
void wsqe_kernel(const int* __restrict__ x,
                 const float* __restrict__ arch_prob,
                 const float* __restrict__ codebooks,
                 const int* __restrict__ cb_index,
                 float* __restrict__ out) {
    const int gid     = blockIdx.x * 256 + threadIdx.x;
    const int t       = gid & 15;          // sub-lane within cluster
    const int cluster = gid >> 4;
    const int bf0     = cluster * G;       // first bf of this thread's batch
    const int m       = t >> 2;            // this thread's sub-codebook

    // ---- batched x load: 8 consecutive ints (32B aligned), streaming ----
    const i32x4 xa = __builtin_nontemporal_load(
        reinterpret_cast<const i32x4*>(x + bf0));
    const i32x4 xb = __builtin_nontemporal_load(
        reinterpret_cast<const i32x4*>(x + bf0 + 4));
    const int xs[G] = {xa.x, xa.y, xa.z, xa.w, xb.x, xb.y, xb.z, xb.w};

    int fs[G];
    {
        int f0 = bf0 % F;
        #pragma unroll
        for (int g = 0; g < G; ++g) {
            fs[g] = f0;
            f0 = (f0 + 1 == F) ? 0 : f0 + 1;
        }
    }

    // ---- issue all G*A = 32 independent scattered kv gathers (streaming) ----
    int kv[G][A];
    #pragma unroll
    for (int g = 0; g < G; ++g) {
        const int xo4 = (xs[g] + fs[g] * FIELD) << 2;
        #pragma unroll
        for (int a = 0; a < A; ++a) {
            kv[g][a] = __builtin_nontemporal_load(
                cb_index + (a * (V * M)) + xo4 + m);
        }
    }

    // ---- per-g: codebook loads (cached), weighted sum, plain store ----
    #pragma unroll
    for (int g = 0; g < G; ++g) {
        const float* cbase = codebooks + fs[g] * (MAXK * D) + (t << 2);
        const float4 v0 = *reinterpret_cast<const float4*>(cbase + kv[g][0] * D);
        const float4 v1 = *reinterpret_cast<const float4*>(cbase + kv[g][1] * D);
        const float4 v2 = *reinterpret_cast<const float4*>(cbase + kv[g][2] * D);
        const float4 v3 = *reinterpret_cast<const float4*>(cbase + kv[g][3] * D);

        const float4 w = *reinterpret_cast<const float4*>(arch_prob + fs[g] * A);
        float4 acc;
        acc.x = w.x * v0.x; acc.y = w.x * v0.y;
        acc.z = w.x * v0.z; acc.w = w.x * v0.w;
        acc.x = fmaf(w.y, v1.x, acc.x); acc.y = fmaf(w.y, v1.y, acc.y);
        acc.z = fmaf(w.y, v1.z, acc.z); acc.w = fmaf(w.y, v1.w, acc.w);
        acc.x = fmaf(w.z, v2.x, acc.x); acc.y = fmaf(w.z, v2.y, acc.y);
        acc.z = fmaf(w.z, v2.z, acc.z); acc.w = fmaf(w.z, v2.w, acc.w);
        acc.x = fmaf(w.w, v3.x, acc.x); acc.y = fmaf(w.w, v3.y, acc.y);
        acc.z = fmaf(w.w, v3.z, acc.z); acc.w = fmaf(w.w, v3.w, acc.w);

        *reinterpret_cast<float4*>(out + (size_t)(bf0 + g) * D + (t << 2)) = acc;
    }
}

extern "C" void kernel_launch(void* const* d_in, const int* in_sizes, int n_in,
                              void* d_out, int out_size, void* d_ws, size_t ws_size,
                              hipStream_t stream) {
    const int*   x         = (const int*)d_in[0];
    const float* arch_prob = (const float*)d_in[1];
    const float* codebooks = (const float*)d_in[2];
    const int*   cb_index  = (const int*)d_in[3];
    float*       out       = (float*)d_out;

    // clusters = B*F/G = 20,480 ; threads = 327,680 ; blocks = 1,280 (exact)
    const int total  = (B * F / G) * 16;
    const int blocks = total / 256;
    wsqe_kernel<<<blocks, 256, 0, stream>>>(x, arch_prob, codebooks, cb_index, out);
}